// Round 1
// baseline (339.491 us; speedup 1.0000x reference)
//
#include <hip/hip_runtime.h>

// Mamba2 quantized decode step, MI355X/gfx950.
// Pipeline: quant(hidden,W_in,W_out) -> GEMM1(bf16 MFMA, int-exact) -> xBC fake-quant
//           -> SSM contraction (y = sc*(S@C) + dt*(B.C)*x, state NOT written back)
//           -> epilogue (fq -> +D*x -> *relu(z) -> fq) -> GEMM2 (bf16 MFMA).
// Workspace requirement: ~55 MB.

#define B_       64
#define DMODEL   2048
#define DSSM     4096
#define NH       64
#define HD       64
#define DSTATE   128
#define DPROJ    8512
#define XBCLEN   4352   // DSSM + 2*DSTATE

typedef __attribute__((ext_vector_type(8))) short short8;
typedef __attribute__((ext_vector_type(4))) float floatx4;

__device__ __forceinline__ float blockMax256(float v, float* sm) {
  #pragma unroll
  for (int off = 32; off > 0; off >>= 1)
    v = fmaxf(v, __shfl_xor(v, off, 64));
  __syncthreads();                       // protect sm from previous use
  if ((threadIdx.x & 63) == 0) sm[threadIdx.x >> 6] = v;
  __syncthreads();
  return fmaxf(fmaxf(sm[0], sm[1]), fmaxf(sm[2], sm[3]));
}

// int-valued float (|v|<=127) -> bf16 bits; exact (needs <=7 mantissa bits)
__device__ __forceinline__ unsigned short bf16_of_int(float q) {
  return (unsigned short)(__float_as_uint(q) >> 16);
}

// ---------- row-wise fake-quant: fp32 [rows x COLS] -> bf16 int levels + scale ----------
template<int COLS>
__global__ __launch_bounds__(256) void quant_rows(const float* __restrict__ in,
                                                  unsigned short* __restrict__ outq,
                                                  float* __restrict__ scales) {
  __shared__ float sm[4];
  constexpr int NV = COLS / 1024;        // float4s per thread (256 threads)
  int r = blockIdx.x;
  const float4* row = (const float4*)(in + (size_t)r * COLS);
  float4 v[NV];
  float m = 0.f;
  #pragma unroll
  for (int i = 0; i < NV; i++) {
    v[i] = row[threadIdx.x + i * 256];
    m = fmaxf(m, fmaxf(fmaxf(fabsf(v[i].x), fabsf(v[i].y)),
                       fmaxf(fabsf(v[i].z), fabsf(v[i].w))));
  }
  float s = blockMax256(m, sm) * (1.0f / 127.0f);
  if (s == 0.f) s = 1.f;
  if (threadIdx.x == 0) scales[r] = s;
  unsigned short* orow = outq + (size_t)r * COLS;
  #pragma unroll
  for (int i = 0; i < NV; i++) {
    int idx = (threadIdx.x + i * 256) * 4;
    ushort4 o;
    o.x = bf16_of_int(rintf(v[i].x / s));
    o.y = bf16_of_int(rintf(v[i].y / s));
    o.z = bf16_of_int(rintf(v[i].z / s));
    o.w = bf16_of_int(rintf(v[i].w / s));
    *(ushort4*)(orow + idx) = o;
  }
}

// ---------- GEMM: C[m][n] (+)= sA[m]*sB[n] * sum_k Aq[m][k]*Bq[n][k] ----------
// M=64 fixed. Block = 4 waves, each wave: 16 n-cols x 64 m-rows (4 MFMA acc).
// Grid: (N/64, ksplit); partials accumulated with fp32 atomics (Cout pre-zeroed).
__global__ __launch_bounds__(256) void gemm_q(
    const unsigned short* __restrict__ A, int lda, const float* __restrict__ sA,
    const unsigned short* __restrict__ Bq, int ldb, const float* __restrict__ sB,
    float* __restrict__ Cout, int N, int kchunk) {
  int wave = threadIdx.x >> 6;
  int lane = threadIdx.x & 63;
  int l16 = lane & 15, quad = lane >> 4;
  int n0 = blockIdx.x * 64 + wave * 16;
  int k0 = blockIdx.y * kchunk;
  floatx4 zero = {0.f, 0.f, 0.f, 0.f};
  floatx4 acc[4] = {zero, zero, zero, zero};
  const unsigned short* brow = Bq + (size_t)(n0 + l16) * ldb;
  for (int k = k0; k < k0 + kchunk; k += 32) {
    int koff = k + quad * 8;
    short8 bfrag = *(const short8*)(brow + koff);
    #pragma unroll
    for (int mt = 0; mt < 4; mt++) {
      short8 afrag = *(const short8*)(A + (size_t)(mt * 16 + l16) * lda + koff);
      acc[mt] = __builtin_amdgcn_mfma_f32_16x16x32_bf16(afrag, bfrag, acc[mt], 0, 0, 0);
    }
  }
  int ncol = n0 + l16;
  float sb = sB[ncol];
  #pragma unroll
  for (int mt = 0; mt < 4; mt++) {
    #pragma unroll
    for (int r = 0; r < 4; r++) {
      int m = mt * 16 + quad * 4 + r;   // C/D: col=lane&15, row=quad*4+reg (m89)
      atomicAdd(&Cout[(size_t)m * N + ncol], acc[mt][r] * sA[m] * sb);
    }
  }
}

// ---------- xBC fake-quant (per batch row, 4352 wide) ----------
__global__ __launch_bounds__(256) void kxbc(const float* __restrict__ zxb,
                                            float* __restrict__ xbcq) {
  __shared__ float sm[4];
  int b = blockIdx.x;
  const float* row = zxb + (size_t)b * DPROJ + DSSM;
  float4 v[5];
  float m = 0.f;
  #pragma unroll
  for (int i = 0; i < 5; i++) {
    int idx = threadIdx.x * 4 + i * 1024;
    if (idx < XBCLEN) {
      v[i] = *(const float4*)(row + idx);
      m = fmaxf(m, fmaxf(fmaxf(fabsf(v[i].x), fabsf(v[i].y)),
                         fmaxf(fabsf(v[i].z), fabsf(v[i].w))));
    }
  }
  float s = blockMax256(m, sm) * (1.0f / 127.0f);
  if (s == 0.f) s = 1.f;
  float* orow = xbcq + (size_t)b * XBCLEN;
  #pragma unroll
  for (int i = 0; i < 5; i++) {
    int idx = threadIdx.x * 4 + i * 1024;
    if (idx < XBCLEN) {
      float4 q;
      q.x = rintf(v[i].x / s) * s;
      q.y = rintf(v[i].y / s) * s;
      q.z = rintf(v[i].z / s) * s;
      q.w = rintf(v[i].w / s) * s;
      *(float4*)(orow + idx) = q;
    }
  }
}

// ---------- SSM contraction: one block per (b,h), streams 32KB of state ----------
__global__ __launch_bounds__(256) void ky(const float* __restrict__ state,
                                          const float* __restrict__ zxb,
                                          const float* __restrict__ xbcq,
                                          const float* __restrict__ dt_bias,
                                          const float* __restrict__ A_log,
                                          float* __restrict__ yraw) {
  __shared__ float sh[3];   // 0: B.C  1: dt  2: scale
  int h = blockIdx.x, b = blockIdx.y;
  int t = threadIdx.x;
  const float* xrow = xbcq + (size_t)b * XBCLEN;
  const float* Bv = xrow + DSSM;          // [4096,4224)
  const float* Cv = xrow + DSSM + DSTATE; // [4224,4352)
  int nb = (t * 4) & 127;
  float4 c4 = *(const float4*)(Cv + nb);
  if (t < 64) {
    float p = Bv[t] * Cv[t] + Bv[t + 64] * Cv[t + 64];
    #pragma unroll
    for (int off = 32; off > 0; off >>= 1) p += __shfl_xor(p, off, 64);
    if (t == 0) sh[0] = p;
  } else if (t == 64) {
    float dtv = zxb[(size_t)b * DPROJ + (DPROJ - NH) + h] + dt_bias[h];
    if (dtv < -2.f) dtv = 0.f;
    else if (dtv <= 2.f)
      dtv = 0.6931471805599453f + 0.5f * dtv + dtv * dtv * (1.f / 8.f)
            + dtv * dtv * dtv * (1.f / 48.f);
    float A = -expf(A_log[h]);
    float dA = fmaxf(dtv * A, -10000.f);
    float e = 1.f + dA + dA * dA * (1.f / 2.f) + dA * dA * dA * (1.f / 6.f)
              + dA * dA * dA * dA * (1.f / 24.f)
              + dA * dA * dA * dA * dA * (1.f / 120.f);
    e = fminf(fmaxf(e, 0.f), 1.f);
    sh[1] = dtv; sh[2] = e;
  }
  __syncthreads();
  float coef = sh[1] * sh[0];   // dt * (B.C)
  float sc = sh[2];
  const float4* st = (const float4*)(state + ((size_t)b * NH + h) * (HD * DSTATE));
  #pragma unroll
  for (int it = 0; it < 8; it++) {
    float4 s4 = st[t + it * 256];
    float acc = s4.x * c4.x + s4.y * c4.y + s4.z * c4.z + s4.w * c4.w;
    #pragma unroll
    for (int off = 1; off < 32; off <<= 1) acc += __shfl_xor(acc, off, 64);
    if ((t & 31) == 0) {
      int p = it * 8 + (t >> 5);
      int d = h * HD + p;
      yraw[(size_t)b * DSSM + d] = sc * acc + coef * xrow[d];
    }
  }
}

// ---------- epilogue: fq(y) -> +D*x -> *relu(z) -> fq -> bf16 int levels ----------
__global__ __launch_bounds__(256) void kepi(const float* __restrict__ yraw,
                                            const float* __restrict__ zxb,
                                            const float* __restrict__ xbcq,
                                            const float* __restrict__ Dv,
                                            unsigned short* __restrict__ q3,
                                            float* __restrict__ sy) {
  __shared__ float sm[4];
  int b = blockIdx.x, t = threadIdx.x;
  const float* yrow = yraw + (size_t)b * DSSM;
  float4 yv[4];
  float m = 0.f;
  #pragma unroll
  for (int i = 0; i < 4; i++) {
    yv[i] = *(const float4*)(yrow + t * 4 + i * 1024);
    m = fmaxf(m, fmaxf(fmaxf(fabsf(yv[i].x), fabsf(yv[i].y)),
                       fmaxf(fabsf(yv[i].z), fabsf(yv[i].w))));
  }
  float s1 = blockMax256(m, sm) * (1.0f / 127.0f);
  if (s1 == 0.f) s1 = 1.f;
  float4 y3[4];
  float m2 = 0.f;
  #pragma unroll
  for (int i = 0; i < 4; i++) {
    int idx = t * 4 + i * 1024;
    float4 x4 = *(const float4*)(xbcq + (size_t)b * XBCLEN + idx);
    float4 z4 = *(const float4*)(zxb + (size_t)b * DPROJ + idx);
    float4 d4 = *(const float4*)(Dv + idx);
    float4 r;
    r.x = (rintf(yv[i].x / s1) * s1 + d4.x * x4.x) * fmaxf(z4.x, 0.f);
    r.y = (rintf(yv[i].y / s1) * s1 + d4.y * x4.y) * fmaxf(z4.y, 0.f);
    r.z = (rintf(yv[i].z / s1) * s1 + d4.z * x4.z) * fmaxf(z4.z, 0.f);
    r.w = (rintf(yv[i].w / s1) * s1 + d4.w * x4.w) * fmaxf(z4.w, 0.f);
    y3[i] = r;
    m2 = fmaxf(m2, fmaxf(fmaxf(fabsf(r.x), fabsf(r.y)),
                         fmaxf(fabsf(r.z), fabsf(r.w))));
  }
  float s3 = blockMax256(m2, sm) * (1.0f / 127.0f);
  if (s3 == 0.f) s3 = 1.f;
  if (t == 0) sy[b] = s3;
  unsigned short* orow = q3 + (size_t)b * DSSM;
  #pragma unroll
  for (int i = 0; i < 4; i++) {
    int idx = t * 4 + i * 1024;
    ushort4 o;
    o.x = bf16_of_int(rintf(y3[i].x / s3));
    o.y = bf16_of_int(rintf(y3[i].y / s3));
    o.z = bf16_of_int(rintf(y3[i].z / s3));
    o.w = bf16_of_int(rintf(y3[i].w / s3));
    *(ushort4*)(orow + idx) = o;
  }
}

extern "C" void kernel_launch(void* const* d_in, const int* in_sizes, int n_in,
                              void* d_out, int out_size, void* d_ws, size_t ws_size,
                              hipStream_t stream) {
  const float* hidden  = (const float*)d_in[0];
  const float* ssm     = (const float*)d_in[1];
  const float* W_in    = (const float*)d_in[2];
  const float* dt_bias = (const float*)d_in[3];
  const float* A_log   = (const float*)d_in[4];
  const float* Dv      = (const float*)d_in[5];
  const float* W_out   = (const float*)d_in[6];
  float* out = (float*)d_out;

  char* p = (char*)d_ws;
  auto alloc = [&](size_t bytes) {
    char* r = p;
    p += (bytes + 255) & ~(size_t)255;
    return r;
  };
  unsigned short* xq   = (unsigned short*)alloc((size_t)B_ * DMODEL * 2);
  unsigned short* winq = (unsigned short*)alloc((size_t)DPROJ * DMODEL * 2);
  unsigned short* woq  = (unsigned short*)alloc((size_t)DMODEL * DSSM * 2);
  unsigned short* q3   = (unsigned short*)alloc((size_t)B_ * DSSM * 2);
  float* sx   = (float*)alloc(B_ * 4);
  float* swin = (float*)alloc(DPROJ * 4);
  float* swo  = (float*)alloc(DMODEL * 4);
  float* sy   = (float*)alloc(B_ * 4);
  float* zxb  = (float*)alloc((size_t)B_ * DPROJ * 4);
  float* xbcq = (float*)alloc((size_t)B_ * XBCLEN * 4);
  float* yraw = (float*)alloc((size_t)B_ * DSSM * 4);

  quant_rows<DMODEL><<<B_, 256, 0, stream>>>(hidden, xq, sx);
  quant_rows<DMODEL><<<DPROJ, 256, 0, stream>>>(W_in, winq, swin);
  quant_rows<DSSM><<<DMODEL, 256, 0, stream>>>(W_out, woq, swo);
  hipMemsetAsync(zxb, 0, (size_t)B_ * DPROJ * 4, stream);
  gemm_q<<<dim3(DPROJ / 64, 4), 256, 0, stream>>>(xq, DMODEL, sx,
                                                  winq, DMODEL, swin,
                                                  zxb, DPROJ, DMODEL / 4);
  kxbc<<<B_, 256, 0, stream>>>(zxb, xbcq);
  ky<<<dim3(NH, B_), 256, 0, stream>>>(ssm, zxb, xbcq, dt_bias, A_log, yraw);
  kepi<<<B_, 256, 0, stream>>>(yraw, zxb, xbcq, Dv, q3, sy);
  hipMemsetAsync(out, 0, (size_t)B_ * DMODEL * 4, stream);
  gemm_q<<<dim3(DMODEL / 64, 8), 256, 0, stream>>>(q3, DSSM, sy,
                                                   woq, DSSM, swo,
                                                   out, DMODEL, DSSM / 8);
}

// Round 2
// 324.318 us; speedup vs baseline: 1.0468x; 1.0468x over previous
//
#include <hip/hip_runtime.h>

// Mamba2 quantized decode step, MI355X/gfx950. Round 2.
// 7 dispatches: kquant_all -> gemm1(partials) -> kmid(reduce+xbc quant+coefs)
//   -> ky(state contraction) -> kepi -> gemm2(partials) -> kout(reduce).
// No atomics, no memsets. GEMMs are int-exact bf16 MFMA with pipelined loads.

#define B_       64
#define DMODEL   2048
#define DSSM     4096
#define NH       64
#define HD       64
#define DSTATE   128
#define DPROJ    8512
#define XBCLEN   4352   // DSSM + 2*DSTATE
#define KS1      8
#define KS2      16

typedef __attribute__((ext_vector_type(8))) short short8;
typedef __attribute__((ext_vector_type(4))) float floatx4;

__device__ __forceinline__ float blockMax256(float v, float* sm) {
  #pragma unroll
  for (int off = 32; off > 0; off >>= 1)
    v = fmaxf(v, __shfl_xor(v, off, 64));
  __syncthreads();                       // protect sm from previous use
  if ((threadIdx.x & 63) == 0) sm[threadIdx.x >> 6] = v;
  __syncthreads();
  return fmaxf(fmaxf(sm[0], sm[1]), fmaxf(sm[2], sm[3]));
}

__device__ __forceinline__ float absmax4(float4 v) {
  return fmaxf(fmaxf(fabsf(v.x), fabsf(v.y)), fmaxf(fabsf(v.z), fabsf(v.w)));
}

// int-valued float (|v|<=127) -> bf16 bits; exact (<=7 mantissa bits)
__device__ __forceinline__ unsigned short bf16_of_int(float q) {
  return (unsigned short)(__float_as_uint(q) >> 16);
}

// ---------- merged row-wise fake-quant for hidden / W_in / W_out ----------
template<int COLS>
__device__ __forceinline__ void qrow(const float* __restrict__ in,
                                     unsigned short* __restrict__ outq,
                                     float* __restrict__ scales, int r, float* sm) {
  constexpr int NV = COLS / 1024;
  const float4* row = (const float4*)(in + (size_t)r * COLS);
  float4 v[NV];
  float m = 0.f;
  #pragma unroll
  for (int i = 0; i < NV; i++) {
    v[i] = row[threadIdx.x + i * 256];
    m = fmaxf(m, absmax4(v[i]));
  }
  float mx = blockMax256(m, sm);
  float s = mx * (1.0f / 127.0f);
  float rs = (s == 0.f) ? 0.f : 127.0f / mx;   // q = rint(v*rs); all-zero row -> q=0
  if (s == 0.f) s = 1.f;
  if (threadIdx.x == 0) scales[r] = s;
  unsigned short* orow = outq + (size_t)r * COLS;
  #pragma unroll
  for (int i = 0; i < NV; i++) {
    int idx = (threadIdx.x + i * 256) * 4;
    ushort4 o;
    o.x = bf16_of_int(rintf(v[i].x * rs));
    o.y = bf16_of_int(rintf(v[i].y * rs));
    o.z = bf16_of_int(rintf(v[i].z * rs));
    o.w = bf16_of_int(rintf(v[i].w * rs));
    *(ushort4*)(orow + idx) = o;
  }
}

__global__ __launch_bounds__(256) void kquant_all(
    const float* __restrict__ hidden, const float* __restrict__ W_in,
    const float* __restrict__ W_out,
    unsigned short* __restrict__ xq, unsigned short* __restrict__ winq,
    unsigned short* __restrict__ woq,
    float* __restrict__ sx, float* __restrict__ swin, float* __restrict__ swo) {
  __shared__ float sm[4];
  int bid = blockIdx.x;
  if (bid < DPROJ)                 qrow<DMODEL>(W_in, winq, swin, bid, sm);
  else if (bid < DPROJ + DMODEL)   qrow<DSSM>(W_out, woq, swo, bid - DPROJ, sm);
  else                             qrow<DMODEL>(hidden, xq, sx, bid - DPROJ - DMODEL, sm);
}

// ---------- GEMM: P[split][m][n] = sA[m]*sB[n] * sum_k Aq[m][k]*Bq[n][k] ----------
// M=64. Block = 4 waves, each wave 16 n-cols x 64 m-rows. Pipelined frag loads.
__global__ __launch_bounds__(256) void gemm_q(
    const unsigned short* __restrict__ A, int lda, const float* __restrict__ sA,
    const unsigned short* __restrict__ Bq, int ldb, const float* __restrict__ sB,
    float* __restrict__ Pout, int N, int kchunk) {
  int wave = threadIdx.x >> 6;
  int lane = threadIdx.x & 63;
  int l16 = lane & 15, quad = lane >> 4;
  int n0 = blockIdx.x * 64 + wave * 16;
  int k0 = blockIdx.y * kchunk;
  floatx4 zero = {0.f, 0.f, 0.f, 0.f};
  floatx4 acc[4] = {zero, zero, zero, zero};
  const unsigned short* brow = Bq + (size_t)(n0 + l16) * ldb + quad * 8;
  const unsigned short* arow = A + (size_t)l16 * lda + quad * 8;
  short8 bnext = *(const short8*)(brow + k0);
  short8 anext[4];
  #pragma unroll
  for (int mt = 0; mt < 4; mt++)
    anext[mt] = *(const short8*)(arow + (size_t)mt * 16 * lda + k0);
  for (int k = k0; k < k0 + kchunk; k += 32) {
    short8 bcur = bnext;
    short8 acur[4] = {anext[0], anext[1], anext[2], anext[3]};
    if (k + 32 < k0 + kchunk) {
      bnext = *(const short8*)(brow + k + 32);
      #pragma unroll
      for (int mt = 0; mt < 4; mt++)
        anext[mt] = *(const short8*)(arow + (size_t)mt * 16 * lda + k + 32);
    }
    #pragma unroll
    for (int mt = 0; mt < 4; mt++)
      acc[mt] = __builtin_amdgcn_mfma_f32_16x16x32_bf16(acur[mt], bcur, acc[mt], 0, 0, 0);
  }
  int ncol = n0 + l16;
  float sb = sB[ncol];
  float* pbase = Pout + (size_t)blockIdx.y * 64 * N;
  #pragma unroll
  for (int mt = 0; mt < 4; mt++) {
    #pragma unroll
    for (int r = 0; r < 4; r++) {
      int m = mt * 16 + quad * 4 + r;   // C/D: col=lane&15, row=quad*4+reg (m89)
      pbase[(size_t)m * N + ncol] = acc[mt][r] * sA[m] * sb;
    }
  }
}

// ---------- kmid: reduce GEMM1 partials, split z/xBC/dt, quant xBC, coefs ----------
__global__ __launch_bounds__(256) void kmid(
    const float* __restrict__ P1, const float* __restrict__ dt_bias,
    const float* __restrict__ A_log,
    float* __restrict__ zbuf, float* __restrict__ xbcq, float* __restrict__ coefs) {
  __shared__ float sm[4];
  __shared__ float dts[NH];
  __shared__ float sbc;
  int b = blockIdx.x, t = threadIdx.x;
  float4 v[9];
  float m = 0.f;
  #pragma unroll
  for (int i = 0; i < 9; i++) {
    int idx = t + i * 256;                   // float4 index within 2128-wide row
    if (idx < 2128) {
      const float4* p0 = (const float4*)P1 + (size_t)b * 2128 + idx;
      float4 a = p0[0];
      #pragma unroll
      for (int s = 1; s < KS1; s++) {
        float4 q = p0[(size_t)s * 64 * 2128];
        a.x += q.x; a.y += q.y; a.z += q.z; a.w += q.w;
      }
      v[i] = a;
      if (idx >= 1024 && idx < 2112) m = fmaxf(m, absmax4(a));
      if (idx >= 2112) {                      // dt segment: t in [64,80)
        dts[(t - 64) * 4 + 0] = a.x;
        dts[(t - 64) * 4 + 1] = a.y;
        dts[(t - 64) * 4 + 2] = a.z;
        dts[(t - 64) * 4 + 3] = a.w;
      }
    }
  }
  float mx = blockMax256(m, sm);             // barrier also publishes dts[]
  float s = mx * (1.0f / 127.0f);
  float rs = (s == 0.f) ? 0.f : 127.0f / mx;
  if (s == 0.f) s = 1.f;
  // z part + quantized xBC part
  float4 q8 = {0.f, 0.f, 0.f, 0.f};          // quantized i==8 f4 (B/C values), t<64
  #pragma unroll
  for (int i = 0; i < 9; i++) {
    int idx = t + i * 256;
    if (idx < 1024) {
      *((float4*)(zbuf + (size_t)b * DSSM) + idx) = v[i];
    } else if (idx < 2112) {
      float4 q;
      q.x = rintf(v[i].x * rs) * s;
      q.y = rintf(v[i].y * rs) * s;
      q.z = rintf(v[i].z * rs) * s;
      q.w = rintf(v[i].w * rs) * s;
      if (i == 8) q8 = q;
      *((float4*)(xbcq + (size_t)b * XBCLEN) + (idx - 1024)) = q;
    }
  }
  // B.C from quantized values: lanes 0..31 hold B f4s, 32..63 hold C f4s (wave 0)
  float4 oth;
  oth.x = __shfl(q8.x, (t & 63) ^ 32, 64);
  oth.y = __shfl(q8.y, (t & 63) ^ 32, 64);
  oth.z = __shfl(q8.z, (t & 63) ^ 32, 64);
  oth.w = __shfl(q8.w, (t & 63) ^ 32, 64);
  float p = 0.f;
  if (t < 32) p = q8.x * oth.x + q8.y * oth.y + q8.z * oth.z + q8.w * oth.w;
  #pragma unroll
  for (int off = 1; off < 32; off <<= 1) p += __shfl_xor(p, off, 64);
  if (t == 0) sbc = p;
  __syncthreads();
  if (t < NH) {
    float dtv = dts[t] + dt_bias[t];
    if (dtv < -2.f) dtv = 0.f;
    else if (dtv <= 2.f)
      dtv = 0.6931471805599453f + 0.5f * dtv + dtv * dtv * (1.f / 8.f)
            + dtv * dtv * dtv * (1.f / 48.f);
    float A = -expf(A_log[t]);
    float dA = fmaxf(dtv * A, -10000.f);
    float e = 1.f + dA + dA * dA * (1.f / 2.f) + dA * dA * dA * (1.f / 6.f)
              + dA * dA * dA * dA * (1.f / 24.f)
              + dA * dA * dA * dA * dA * (1.f / 120.f);
    e = fminf(fmaxf(e, 0.f), 1.f);
    coefs[((size_t)b * NH + t) * 2 + 0] = e;           // sc
    coefs[((size_t)b * NH + t) * 2 + 1] = dtv * sbc;   // dt*(B.C)
  }
}

// ---------- SSM contraction: block per (b,h); 16 lanes per p-row ----------
__global__ __launch_bounds__(256) void ky(const float* __restrict__ state,
                                          const float* __restrict__ xbcq,
                                          const float* __restrict__ coefs,
                                          float* __restrict__ yraw) {
  int h = blockIdx.x, b = blockIdx.y, t = threadIdx.x;
  const float* xrow = xbcq + (size_t)b * XBCLEN;
  const float* Cv = xrow + DSSM + DSTATE;
  int nc = (t & 15) * 8;
  float4 c4a = *(const float4*)(Cv + nc);
  float4 c4b = *(const float4*)(Cv + nc + 4);
  float2 cf = *(const float2*)(coefs + ((size_t)b * NH + h) * 2);  // {sc, coef}
  const float4* st = (const float4*)(state + ((size_t)b * NH + h) * (HD * DSTATE));
  #pragma unroll
  for (int j = 0; j < 4; j++) {
    int r = j * 16 + (t >> 4);
    int base = r * 32 + (t & 15) * 2;
    float4 s0 = st[base], s1 = st[base + 1];
    float acc = s0.x * c4a.x + s0.y * c4a.y + s0.z * c4a.z + s0.w * c4a.w
              + s1.x * c4b.x + s1.y * c4b.y + s1.z * c4b.z + s1.w * c4b.w;
    #pragma unroll
    for (int off = 1; off < 16; off <<= 1) acc += __shfl_xor(acc, off, 64);
    if ((t & 15) == 0) {
      int d = h * HD + r;
      yraw[(size_t)b * DSSM + d] = cf.x * acc + cf.y * xrow[d];
    }
  }
}

// ---------- epilogue: fq(y) -> +D*x -> *relu(z) -> fq -> bf16 int levels ----------
__global__ __launch_bounds__(256) void kepi(const float* __restrict__ yraw,
                                            const float* __restrict__ zbuf,
                                            const float* __restrict__ xbcq,
                                            const float* __restrict__ Dv,
                                            unsigned short* __restrict__ q3,
                                            float* __restrict__ sy) {
  __shared__ float sm[4];
  int b = blockIdx.x, t = threadIdx.x;
  const float* yrow = yraw + (size_t)b * DSSM;
  float4 yv[4];
  float m = 0.f;
  #pragma unroll
  for (int i = 0; i < 4; i++) {
    yv[i] = *(const float4*)(yrow + t * 4 + i * 1024);
    m = fmaxf(m, absmax4(yv[i]));
  }
  float mx1 = blockMax256(m, sm);
  float s1 = mx1 * (1.0f / 127.0f);
  float rs1 = (s1 == 0.f) ? 0.f : 127.0f / mx1;
  if (s1 == 0.f) s1 = 1.f;
  float4 y3[4];
  float m2 = 0.f;
  #pragma unroll
  for (int i = 0; i < 4; i++) {
    int idx = t * 4 + i * 1024;
    float4 x4 = *(const float4*)(xbcq + (size_t)b * XBCLEN + idx);
    float4 z4 = *(const float4*)(zbuf + (size_t)b * DSSM + idx);
    float4 d4 = *(const float4*)(Dv + idx);
    float4 r;
    r.x = (rintf(yv[i].x * rs1) * s1 + d4.x * x4.x) * fmaxf(z4.x, 0.f);
    r.y = (rintf(yv[i].y * rs1) * s1 + d4.y * x4.y) * fmaxf(z4.y, 0.f);
    r.z = (rintf(yv[i].z * rs1) * s1 + d4.z * x4.z) * fmaxf(z4.z, 0.f);
    r.w = (rintf(yv[i].w * rs1) * s1 + d4.w * x4.w) * fmaxf(z4.w, 0.f);
    y3[i] = r;
    m2 = fmaxf(m2, absmax4(r));
  }
  float mx3 = blockMax256(m2, sm);
  float s3 = mx3 * (1.0f / 127.0f);
  float rs3 = (s3 == 0.f) ? 0.f : 127.0f / mx3;
  if (s3 == 0.f) s3 = 1.f;
  if (t == 0) sy[b] = s3;
  unsigned short* orow = q3 + (size_t)b * DSSM;
  #pragma unroll
  for (int i = 0; i < 4; i++) {
    int idx = t * 4 + i * 1024;
    ushort4 o;
    o.x = bf16_of_int(rintf(y3[i].x * rs3));
    o.y = bf16_of_int(rintf(y3[i].y * rs3));
    o.z = bf16_of_int(rintf(y3[i].z * rs3));
    o.w = bf16_of_int(rintf(y3[i].w * rs3));
    *(ushort4*)(orow + idx) = o;
  }
}

// ---------- reduce GEMM2 partials -> out ----------
__global__ __launch_bounds__(256) void kout(const float* __restrict__ P2,
                                            float* __restrict__ out) {
  int idx = blockIdx.x * 256 + threadIdx.x;   // f4 index over 64*2048/4 = 32768
  const float4* p = (const float4*)P2;
  float4 s = p[idx];
  #pragma unroll
  for (int i = 1; i < KS2; i++) {
    float4 a = p[(size_t)i * 32768 + idx];
    s.x += a.x; s.y += a.y; s.z += a.z; s.w += a.w;
  }
  ((float4*)out)[idx] = s;
}

extern "C" void kernel_launch(void* const* d_in, const int* in_sizes, int n_in,
                              void* d_out, int out_size, void* d_ws, size_t ws_size,
                              hipStream_t stream) {
  const float* hidden  = (const float*)d_in[0];
  const float* ssm     = (const float*)d_in[1];
  const float* W_in    = (const float*)d_in[2];
  const float* dt_bias = (const float*)d_in[3];
  const float* A_log   = (const float*)d_in[4];
  const float* Dv      = (const float*)d_in[5];
  const float* W_out   = (const float*)d_in[6];
  float* out = (float*)d_out;

  char* p = (char*)d_ws;
  auto alloc = [&](size_t bytes) {
    char* r = p;
    p += (bytes + 255) & ~(size_t)255;
    return r;
  };
  unsigned short* xq   = (unsigned short*)alloc((size_t)B_ * DMODEL * 2);
  unsigned short* winq = (unsigned short*)alloc((size_t)DPROJ * DMODEL * 2);
  unsigned short* woq  = (unsigned short*)alloc((size_t)DMODEL * DSSM * 2);
  unsigned short* q3   = (unsigned short*)alloc((size_t)B_ * DSSM * 2);
  float* sx    = (float*)alloc(B_ * 4);
  float* swin  = (float*)alloc(DPROJ * 4);
  float* swo   = (float*)alloc(DMODEL * 4);
  float* sy    = (float*)alloc(B_ * 4);
  float* P1    = (float*)alloc((size_t)KS1 * B_ * DPROJ * 4);   // 17.4 MB
  float* P2    = (float*)alloc((size_t)KS2 * B_ * DMODEL * 4);  // 8 MB
  float* zbuf  = (float*)alloc((size_t)B_ * DSSM * 4);
  float* xbcq  = (float*)alloc((size_t)B_ * XBCLEN * 4);
  float* coefs = (float*)alloc((size_t)B_ * NH * 2 * 4);
  float* yraw  = (float*)alloc((size_t)B_ * DSSM * 4);

  kquant_all<<<DPROJ + DMODEL + B_, 256, 0, stream>>>(hidden, W_in, W_out,
                                                      xq, winq, woq, sx, swin, swo);
  gemm_q<<<dim3(DPROJ / 64, KS1), 256, 0, stream>>>(xq, DMODEL, sx,
                                                    winq, DMODEL, swin,
                                                    P1, DPROJ, DMODEL / KS1);
  kmid<<<B_, 256, 0, stream>>>(P1, dt_bias, A_log, zbuf, xbcq, coefs);
  ky<<<dim3(NH, B_), 256, 0, stream>>>(ssm, xbcq, coefs, yraw);
  kepi<<<B_, 256, 0, stream>>>(yraw, zbuf, xbcq, Dv, q3, sy);
  gemm_q<<<dim3(DMODEL / 64, KS2), 256, 0, stream>>>(q3, DSSM, sy,
                                                     woq, DSSM, swo,
                                                     P2, DMODEL, DSSM / KS2);
  kout<<<DMODEL / 16, 256, 0, stream>>>(P2, out);
}

// Round 3
// 309.058 us; speedup vs baseline: 1.0985x; 1.0494x over previous
//
#include <hip/hip_runtime.h>

// Mamba2 quantized decode step, MI355X/gfx950. Round 3.
// int8 everywhere: quantized operands stored as int8, GEMMs use
// mfma_i32_16x16x64_i8 (int32 accum, exact). 7 dispatches:
// kquant_all -> gemm1 -> kmid -> ky -> kepi -> gemm2 -> kout.

#define B_       64
#define DMODEL   2048
#define DSSM     4096
#define NH       64
#define HD       64
#define DSTATE   128
#define DPROJ    8512
#define XBCLEN   4352   // DSSM + 2*DSTATE
#define KS1      8
#define KS2      16

typedef __attribute__((ext_vector_type(4))) int int4v;

__device__ __forceinline__ float blockMax256(float v, float* sm) {
  #pragma unroll
  for (int off = 32; off > 0; off >>= 1)
    v = fmaxf(v, __shfl_xor(v, off, 64));
  __syncthreads();                       // protect sm from previous use
  if ((threadIdx.x & 63) == 0) sm[threadIdx.x >> 6] = v;
  __syncthreads();
  return fmaxf(fmaxf(sm[0], sm[1]), fmaxf(sm[2], sm[3]));
}

__device__ __forceinline__ float absmax4(float4 v) {
  return fmaxf(fmaxf(fabsf(v.x), fabsf(v.y)), fmaxf(fabsf(v.z), fabsf(v.w)));
}

__device__ __forceinline__ unsigned int pack4(float a, float b, float c, float d,
                                              float rs) {
  int c0 = (int)rintf(a * rs), c1 = (int)rintf(b * rs);
  int c2 = (int)rintf(c * rs), c3 = (int)rintf(d * rs);
  return (unsigned)(c0 & 255) | ((unsigned)(c1 & 255) << 8) |
         ((unsigned)(c2 & 255) << 16) | ((unsigned)(c3 & 255) << 24);
}

// ---------- merged row-wise fake-quant -> int8 levels + scale ----------
template<int COLS>
__device__ __forceinline__ void qrow8(const float* __restrict__ in,
                                      unsigned int* __restrict__ outq,
                                      float* __restrict__ scales, int r, float* sm) {
  constexpr int NV = COLS / 1024;
  const float4* row = (const float4*)(in + (size_t)r * COLS);
  float4 v[NV];
  float m = 0.f;
  #pragma unroll
  for (int i = 0; i < NV; i++) {
    v[i] = row[threadIdx.x + i * 256];
    m = fmaxf(m, absmax4(v[i]));
  }
  float mx = blockMax256(m, sm);
  float s = mx * (1.0f / 127.0f);
  float rs = (s == 0.f) ? 0.f : 127.0f / mx;
  if (s == 0.f) s = 1.f;
  if (threadIdx.x == 0) scales[r] = s;
  unsigned int* orow = outq + (size_t)r * (COLS / 4);
  #pragma unroll
  for (int i = 0; i < NV; i++)
    orow[threadIdx.x + i * 256] = pack4(v[i].x, v[i].y, v[i].z, v[i].w, rs);
}

__global__ __launch_bounds__(256) void kquant_all(
    const float* __restrict__ hidden, const float* __restrict__ W_in,
    const float* __restrict__ W_out,
    unsigned int* __restrict__ xq, unsigned int* __restrict__ winq,
    unsigned int* __restrict__ woq,
    float* __restrict__ sx, float* __restrict__ swin, float* __restrict__ swo) {
  __shared__ float sm[4];
  int bid = blockIdx.x;
  if (bid < DPROJ)                 qrow8<DMODEL>(W_in, winq, swin, bid, sm);
  else if (bid < DPROJ + DMODEL)   qrow8<DSSM>(W_out, woq, swo, bid - DPROJ, sm);
  else                             qrow8<DMODEL>(hidden, xq, sx, bid - DPROJ - DMODEL, sm);
}

// ---------- int8 GEMM: P[split][m][n] = sA[m]*sB[n]*sum_k Aq[m][k]*Bq[n][k] ----------
// M=64. Block = 4 waves, each wave 16 n-cols x 64 m-rows. K=64 per MFMA.
__global__ __launch_bounds__(256) void gemm_q8(
    const char* __restrict__ A, int lda, const float* __restrict__ sA,
    const char* __restrict__ Bq, int ldb, const float* __restrict__ sB,
    float* __restrict__ Pout, int N, int kchunk) {
  int wave = threadIdx.x >> 6;
  int lane = threadIdx.x & 63;
  int l16 = lane & 15, quad = lane >> 4;
  int n0 = blockIdx.x * 64 + wave * 16;
  int k0 = blockIdx.y * kchunk;
  int4v zero = {0, 0, 0, 0};
  int4v acc[4] = {zero, zero, zero, zero};
  const char* brow = Bq + (size_t)(n0 + l16) * ldb + quad * 16;
  const char* arow = A + (size_t)l16 * lda + quad * 16;
  int4v bnext = *(const int4v*)(brow + k0);
  int4v anext[4];
  #pragma unroll
  for (int mt = 0; mt < 4; mt++)
    anext[mt] = *(const int4v*)(arow + (size_t)mt * 16 * lda + k0);
  for (int k = k0; k < k0 + kchunk; k += 64) {
    int4v bcur = bnext;
    int4v acur[4] = {anext[0], anext[1], anext[2], anext[3]};
    if (k + 64 < k0 + kchunk) {
      bnext = *(const int4v*)(brow + k + 64);
      #pragma unroll
      for (int mt = 0; mt < 4; mt++)
        anext[mt] = *(const int4v*)(arow + (size_t)mt * 16 * lda + k + 64);
    }
    #pragma unroll
    for (int mt = 0; mt < 4; mt++)
      acc[mt] = __builtin_amdgcn_mfma_i32_16x16x64_i8(acur[mt], bcur, acc[mt], 0, 0, 0);
  }
  int ncol = n0 + l16;
  float sb = sB[ncol];
  float* pbase = Pout + (size_t)blockIdx.y * 64 * N;
  #pragma unroll
  for (int mt = 0; mt < 4; mt++) {
    #pragma unroll
    for (int r = 0; r < 4; r++) {
      int m = mt * 16 + quad * 4 + r;   // C/D: col=lane&15, row=quad*4+reg (m89)
      pbase[(size_t)m * N + ncol] = (float)acc[mt][r] * sA[m] * sb;
    }
  }
}

// ---------- kmid: reduce GEMM1 partials, split z/xBC/dt, quant xBC, coefs ----------
__global__ __launch_bounds__(256) void kmid(
    const float* __restrict__ P1, const float* __restrict__ dt_bias,
    const float* __restrict__ A_log,
    float* __restrict__ zbuf, float* __restrict__ xbcq, float* __restrict__ coefs) {
  __shared__ float sm[4];
  __shared__ float dts[NH];
  __shared__ float sbc;
  int b = blockIdx.x, t = threadIdx.x;
  float4 v[9];
  float m = 0.f;
  #pragma unroll
  for (int i = 0; i < 9; i++) {
    int idx = t + i * 256;                   // float4 index within 2128-wide row
    if (idx < 2128) {
      const float4* p0 = (const float4*)P1 + (size_t)b * 2128 + idx;
      float4 a = p0[0];
      #pragma unroll
      for (int s = 1; s < KS1; s++) {
        float4 q = p0[(size_t)s * 64 * 2128];
        a.x += q.x; a.y += q.y; a.z += q.z; a.w += q.w;
      }
      v[i] = a;
      if (idx >= 1024 && idx < 2112) m = fmaxf(m, absmax4(a));
      if (idx >= 2112) {                      // dt segment: t in [64,80)
        dts[(t - 64) * 4 + 0] = a.x;
        dts[(t - 64) * 4 + 1] = a.y;
        dts[(t - 64) * 4 + 2] = a.z;
        dts[(t - 64) * 4 + 3] = a.w;
      }
    }
  }
  float mx = blockMax256(m, sm);             // barrier also publishes dts[]
  float s = mx * (1.0f / 127.0f);
  float rs = (s == 0.f) ? 0.f : 127.0f / mx;
  if (s == 0.f) s = 1.f;
  float4 q8 = {0.f, 0.f, 0.f, 0.f};          // quantized i==8 f4 (B/C), t<64
  #pragma unroll
  for (int i = 0; i < 9; i++) {
    int idx = t + i * 256;
    if (idx < 1024) {
      *((float4*)(zbuf + (size_t)b * DSSM) + idx) = v[i];
    } else if (idx < 2112) {
      float4 q;
      q.x = rintf(v[i].x * rs) * s;
      q.y = rintf(v[i].y * rs) * s;
      q.z = rintf(v[i].z * rs) * s;
      q.w = rintf(v[i].w * rs) * s;
      if (i == 8) q8 = q;
      *((float4*)(xbcq + (size_t)b * XBCLEN) + (idx - 1024)) = q;
    }
  }
  // B.C from quantized values: lanes 0..31 hold B f4s, 32..63 hold C f4s (wave 0)
  float4 oth;
  oth.x = __shfl(q8.x, (t & 63) ^ 32, 64);
  oth.y = __shfl(q8.y, (t & 63) ^ 32, 64);
  oth.z = __shfl(q8.z, (t & 63) ^ 32, 64);
  oth.w = __shfl(q8.w, (t & 63) ^ 32, 64);
  float p = 0.f;
  if (t < 32) p = q8.x * oth.x + q8.y * oth.y + q8.z * oth.z + q8.w * oth.w;
  #pragma unroll
  for (int off = 1; off < 32; off <<= 1) p += __shfl_xor(p, off, 64);
  if (t == 0) sbc = p;
  __syncthreads();
  if (t < NH) {
    float dtv = dts[t] + dt_bias[t];
    if (dtv < -2.f) dtv = 0.f;
    else if (dtv <= 2.f)
      dtv = 0.6931471805599453f + 0.5f * dtv + dtv * dtv * (1.f / 8.f)
            + dtv * dtv * dtv * (1.f / 48.f);
    float A = -expf(A_log[t]);
    float dA = fmaxf(dtv * A, -10000.f);
    float e = 1.f + dA + dA * dA * (1.f / 2.f) + dA * dA * dA * (1.f / 6.f)
              + dA * dA * dA * dA * (1.f / 24.f)
              + dA * dA * dA * dA * dA * (1.f / 120.f);
    e = fminf(fmaxf(e, 0.f), 1.f);
    coefs[((size_t)b * NH + t) * 2 + 0] = e;           // sc
    coefs[((size_t)b * NH + t) * 2 + 1] = dtv * sbc;   // dt*(B.C)
  }
}

// ---------- SSM contraction: block per (b,h); fully contiguous loads ----------
__global__ __launch_bounds__(256) void ky(const float* __restrict__ state,
                                          const float* __restrict__ xbcq,
                                          const float* __restrict__ coefs,
                                          float* __restrict__ yraw) {
  int h = blockIdx.x, b = blockIdx.y, t = threadIdx.x;
  const float* xrow = xbcq + (size_t)b * XBCLEN;
  const float* Cv = xrow + DSSM + DSTATE;
  float4 c4 = *(const float4*)(Cv + (t & 31) * 4);
  float2 cf = *(const float2*)(coefs + ((size_t)b * NH + h) * 2);  // {sc, coef}
  const float4* st = (const float4*)(state + ((size_t)b * NH + h) * (HD * DSTATE));
  #pragma unroll
  for (int j = 0; j < 8; j++) {
    float4 s4 = st[j * 256 + t];             // f4 idx i: row=i>>5, n=(i&31)*4
    float acc = s4.x * c4.x + s4.y * c4.y + s4.z * c4.z + s4.w * c4.w;
    #pragma unroll
    for (int off = 1; off < 32; off <<= 1) acc += __shfl_xor(acc, off, 64);
    if ((t & 31) == 0) {
      int r = j * 8 + (t >> 5);
      int d = h * HD + r;
      yraw[(size_t)b * DSSM + d] = cf.x * acc + cf.y * xrow[d];
    }
  }
}

// ---------- epilogue: fq(y) -> +D*x -> *relu(z) -> fq -> int8 levels ----------
__global__ __launch_bounds__(256) void kepi(const float* __restrict__ yraw,
                                            const float* __restrict__ zbuf,
                                            const float* __restrict__ xbcq,
                                            const float* __restrict__ Dv,
                                            unsigned int* __restrict__ q3,
                                            float* __restrict__ sy) {
  __shared__ float sm[4];
  int b = blockIdx.x, t = threadIdx.x;
  const float* yrow = yraw + (size_t)b * DSSM;
  float4 yv[4];
  float m = 0.f;
  #pragma unroll
  for (int i = 0; i < 4; i++) {
    yv[i] = *(const float4*)(yrow + t * 4 + i * 1024);
    m = fmaxf(m, absmax4(yv[i]));
  }
  float mx1 = blockMax256(m, sm);
  float s1 = mx1 * (1.0f / 127.0f);
  float rs1 = (s1 == 0.f) ? 0.f : 127.0f / mx1;
  if (s1 == 0.f) s1 = 1.f;
  float4 y3[4];
  float m2 = 0.f;
  #pragma unroll
  for (int i = 0; i < 4; i++) {
    int idx = t * 4 + i * 1024;
    float4 x4 = *(const float4*)(xbcq + (size_t)b * XBCLEN + idx);
    float4 z4 = *(const float4*)(zbuf + (size_t)b * DSSM + idx);
    float4 d4 = *(const float4*)(Dv + idx);
    float4 r;
    r.x = (rintf(yv[i].x * rs1) * s1 + d4.x * x4.x) * fmaxf(z4.x, 0.f);
    r.y = (rintf(yv[i].y * rs1) * s1 + d4.y * x4.y) * fmaxf(z4.y, 0.f);
    r.z = (rintf(yv[i].z * rs1) * s1 + d4.z * x4.z) * fmaxf(z4.z, 0.f);
    r.w = (rintf(yv[i].w * rs1) * s1 + d4.w * x4.w) * fmaxf(z4.w, 0.f);
    y3[i] = r;
    m2 = fmaxf(m2, absmax4(r));
  }
  float mx3 = blockMax256(m2, sm);
  float s3 = mx3 * (1.0f / 127.0f);
  float rs3 = (s3 == 0.f) ? 0.f : 127.0f / mx3;
  if (s3 == 0.f) s3 = 1.f;
  if (t == 0) sy[b] = s3;
  unsigned int* orow = q3 + (size_t)b * (DSSM / 4);
  #pragma unroll
  for (int i = 0; i < 4; i++)
    orow[t + i * 256] = pack4(y3[i].x, y3[i].y, y3[i].z, y3[i].w, rs3);
}

// ---------- reduce GEMM2 partials -> out ----------
__global__ __launch_bounds__(256) void kout(const float* __restrict__ P2,
                                            float* __restrict__ out) {
  int idx = blockIdx.x * 256 + threadIdx.x;   // f4 index over 64*2048/4 = 32768
  const float4* p = (const float4*)P2;
  float4 s = p[idx];
  #pragma unroll
  for (int i = 1; i < KS2; i++) {
    float4 a = p[(size_t)i * 32768 + idx];
    s.x += a.x; s.y += a.y; s.z += a.z; s.w += a.w;
  }
  ((float4*)out)[idx] = s;
}

extern "C" void kernel_launch(void* const* d_in, const int* in_sizes, int n_in,
                              void* d_out, int out_size, void* d_ws, size_t ws_size,
                              hipStream_t stream) {
  const float* hidden  = (const float*)d_in[0];
  const float* ssm     = (const float*)d_in[1];
  const float* W_in    = (const float*)d_in[2];
  const float* dt_bias = (const float*)d_in[3];
  const float* A_log   = (const float*)d_in[4];
  const float* Dv      = (const float*)d_in[5];
  const float* W_out   = (const float*)d_in[6];
  float* out = (float*)d_out;

  char* p = (char*)d_ws;
  auto alloc = [&](size_t bytes) {
    char* r = p;
    p += (bytes + 255) & ~(size_t)255;
    return r;
  };
  unsigned int* xq   = (unsigned int*)alloc((size_t)B_ * DMODEL);
  unsigned int* winq = (unsigned int*)alloc((size_t)DPROJ * DMODEL);
  unsigned int* woq  = (unsigned int*)alloc((size_t)DMODEL * DSSM);
  unsigned int* q3   = (unsigned int*)alloc((size_t)B_ * DSSM);
  float* sx    = (float*)alloc(B_ * 4);
  float* swin  = (float*)alloc(DPROJ * 4);
  float* swo   = (float*)alloc(DMODEL * 4);
  float* sy    = (float*)alloc(B_ * 4);
  float* P1    = (float*)alloc((size_t)KS1 * B_ * DPROJ * 4);   // 17.4 MB
  float* P2    = (float*)alloc((size_t)KS2 * B_ * DMODEL * 4);  // 8.4 MB
  float* zbuf  = (float*)alloc((size_t)B_ * DSSM * 4);
  float* xbcq  = (float*)alloc((size_t)B_ * XBCLEN * 4);
  float* coefs = (float*)alloc((size_t)B_ * NH * 2 * 4);
  float* yraw  = (float*)alloc((size_t)B_ * DSSM * 4);

  kquant_all<<<DPROJ + DMODEL + B_, 256, 0, stream>>>(hidden, W_in, W_out,
                                                      xq, winq, woq, sx, swin, swo);
  gemm_q8<<<dim3(DPROJ / 64, KS1), 256, 0, stream>>>((const char*)xq, DMODEL, sx,
                                                     (const char*)winq, DMODEL, swin,
                                                     P1, DPROJ, DMODEL / KS1);
  kmid<<<B_, 256, 0, stream>>>(P1, dt_bias, A_log, zbuf, xbcq, coefs);
  ky<<<dim3(NH, B_), 256, 0, stream>>>(ssm, xbcq, coefs, yraw);
  kepi<<<B_, 256, 0, stream>>>(yraw, zbuf, xbcq, Dv, q3, sy);
  gemm_q8<<<dim3(DMODEL / 64, KS2), 256, 0, stream>>>((const char*)q3, DSSM, sy,
                                                      (const char*)woq, DSSM, swo,
                                                      P2, DMODEL, DSSM / KS2);
  kout<<<DMODEL / 16, 256, 0, stream>>>(P2, out);
}